// Round 1
// baseline (365.080 us; speedup 1.0000x reference)
//
#include <hip/hip_runtime.h>
#include <hip/hip_bf16.h>
#include <type_traits>

#define N_ROWS 20000
#define KNBR   32
#define M_ROWS 100000
#define INF    256
#define DIMW   64
#define ATTD   128

// bf16 bits -> float (exact)
__device__ __forceinline__ float bfu(unsigned short s) {
    unsigned u = (unsigned)s << 16;
    return __uint_as_float(u);
}

// ---------------------------------------------------------------------------
// Tiled f32 GEMM: out[(r+rowOffset)][0..127] = A[r][0..F-1] @ W[F][128] (+bias)
// BM=64, BN=128(full), BK=32; 256 threads; per-thread 4x8 microtile.
// ---------------------------------------------------------------------------
template <typename OutT, bool BIAS>
__global__ __launch_bounds__(256) void gemm128(
    const float* __restrict__ A, const float* __restrict__ W,
    OutT* __restrict__ out, const float* __restrict__ bias,
    int R, int F, int rowOffset)
{
    __shared__ float As[32][68];    // transposed: As[kk][row], pad 68
    __shared__ float Ws[32][132];   // Ws[kk][col], pad 132

    const int t  = threadIdx.x;
    const int m0 = blockIdx.x * 64;
    const int tx = t & 15;          // 16 col groups of 8
    const int ty = t >> 4;          // 16 row groups of 4

    float acc[4][8];
    #pragma unroll
    for (int i = 0; i < 4; i++)
        #pragma unroll
        for (int j = 0; j < 8; j++) acc[i][j] = 0.f;

    const int lrow = t >> 2;        // 0..63  (A-tile loader)
    const int lkq  = t & 3;         // 0..3 -> 8 floats each
    const int wrow = t >> 3;        // 0..31  (W-tile loader)
    const int wc   = (t & 7) * 16;

    for (int k0 = 0; k0 < F; k0 += 32) {
        // ---- stage A tile (transposed) ----
        {
            int r = m0 + lrow;
            float4 a0 = make_float4(0.f, 0.f, 0.f, 0.f), a1 = a0;
            if (r < R) {
                const float* ap = A + (size_t)r * F + k0 + lkq * 8;
                a0 = *(const float4*)ap;
                a1 = *(const float4*)(ap + 4);
            }
            const int kb = lkq * 8;
            As[kb + 0][lrow] = a0.x; As[kb + 1][lrow] = a0.y;
            As[kb + 2][lrow] = a0.z; As[kb + 3][lrow] = a0.w;
            As[kb + 4][lrow] = a1.x; As[kb + 5][lrow] = a1.y;
            As[kb + 6][lrow] = a1.z; As[kb + 7][lrow] = a1.w;
        }
        // ---- stage W tile ----
        {
            const float* wp = W + (size_t)(k0 + wrow) * 128 + wc;
            float4 w0 = *(const float4*)(wp + 0);
            float4 w1 = *(const float4*)(wp + 4);
            float4 w2 = *(const float4*)(wp + 8);
            float4 w3 = *(const float4*)(wp + 12);
            *(float4*)&Ws[wrow][wc + 0]  = w0;
            *(float4*)&Ws[wrow][wc + 4]  = w1;
            *(float4*)&Ws[wrow][wc + 8]  = w2;
            *(float4*)&Ws[wrow][wc + 12] = w3;
        }
        __syncthreads();

        #pragma unroll
        for (int kk = 0; kk < 32; kk++) {
            float4 av = *(const float4*)&As[kk][ty * 4];
            float4 w0 = *(const float4*)&Ws[kk][tx * 8];
            float4 w1 = *(const float4*)&Ws[kk][tx * 8 + 4];
            float a[4] = {av.x, av.y, av.z, av.w};
            float w[8] = {w0.x, w0.y, w0.z, w0.w, w1.x, w1.y, w1.z, w1.w};
            #pragma unroll
            for (int i = 0; i < 4; i++)
                #pragma unroll
                for (int j = 0; j < 8; j++)
                    acc[i][j] = fmaf(a[i], w[j], acc[i][j]);
        }
        __syncthreads();
    }

    // ---- store ----
    #pragma unroll
    for (int i = 0; i < 4; i++) {
        int r = m0 + ty * 4 + i;
        if (r >= R) continue;
        OutT* op = out + (size_t)(r + rowOffset) * 128 + tx * 8;
        #pragma unroll
        for (int j = 0; j < 8; j++) {
            float vv = acc[i][j];
            if (BIAS) vv += bias[tx * 8 + j];
            if constexpr (std::is_same_v<OutT, float>) op[j] = vv;
            else op[j] = __float2bfloat16(vv);
        }
    }
}

// ---------------------------------------------------------------------------
// Zero row 0 of both tables (the "no neighbor" padding row).
// ---------------------------------------------------------------------------
template <typename T>
__global__ void zero_row0(T* __restrict__ tabJ, T* __restrict__ tabW) {
    int t = threadIdx.x;     // 128 threads
    tabJ[t] = T(0.0f);
    tabW[t] = T(0.0f);
}

// ---------------------------------------------------------------------------
// Fused score + softmax + weighted gather. One block (256 thr) per n.
//   av[c] = evW1[n][c] + tabJ[j][c] + tabW[w][c]
//   x[k]  = sum_c relu(av[c]) * v[c];  a = softmax_k(x)
//   out[n][f] = sum_k a[k] * ej_p[j_k][f]
// ---------------------------------------------------------------------------
template <typename T>
__global__ __launch_bounds__(256) void score_out(
    const T* __restrict__ tabJ, const T* __restrict__ tabW,
    const float* __restrict__ evW1, const float* __restrict__ ej,
    const int* __restrict__ vj, const int* __restrict__ vw,
    const float* __restrict__ vvec, float* __restrict__ out)
{
    const int n = blockIdx.x;
    const int t = threadIdx.x;

    __shared__ float s_ev[128];
    __shared__ float s_v[128];
    __shared__ int   s_j[32];
    __shared__ int   s_w[32];
    __shared__ float s_a[32];

    if (t < 128) {
        s_ev[t] = evW1[(size_t)n * 128 + t];
        s_v[t]  = vvec[t];
    } else if (t < 160) {
        int k = t - 128;
        s_j[k] = vj[n * KNBR + k];
        s_w[k] = vw[n * KNBR + k];
    }
    __syncthreads();

    // ---- scores: thread t handles k = t>>3, cols [cg*16, cg*16+16) ----
    const int k  = t >> 3;
    const int cg = t & 7;
    const int j  = s_j[k];
    const int w  = s_w[k];

    float x = 0.f;
    {
        const T* tj = tabJ + (size_t)j * 128 + cg * 16;
        const T* tw = tabW + (size_t)w * 128 + cg * 16;
        if constexpr (std::is_same_v<T, float>) {
            const float4* tj4 = (const float4*)tj;
            const float4* tw4 = (const float4*)tw;
            #pragma unroll
            for (int q = 0; q < 4; q++) {
                float4 a4 = tj4[q], b4 = tw4[q];
                float ta[4] = {a4.x, a4.y, a4.z, a4.w};
                float tb[4] = {b4.x, b4.y, b4.z, b4.w};
                #pragma unroll
                for (int e = 0; e < 4; e++) {
                    int c = cg * 16 + q * 4 + e;
                    float av = s_ev[c] + ta[e] + tb[e];
                    x = fmaf(fmaxf(av, 0.f), s_v[c], x);
                }
            }
        } else {
            const uint4* tj4 = (const uint4*)tj;   // 8 bf16 per uint4
            const uint4* tw4 = (const uint4*)tw;
            #pragma unroll
            for (int q = 0; q < 2; q++) {
                uint4 ja = tj4[q], wa = tw4[q];
                unsigned jw[4] = {ja.x, ja.y, ja.z, ja.w};
                unsigned ww[4] = {wa.x, wa.y, wa.z, wa.w};
                #pragma unroll
                for (int p = 0; p < 4; p++) {
                    int c0 = cg * 16 + q * 8 + p * 2;
                    float av0 = s_ev[c0]     + bfu((unsigned short)(jw[p] & 0xffff))
                                             + bfu((unsigned short)(ww[p] & 0xffff));
                    float av1 = s_ev[c0 + 1] + bfu((unsigned short)(jw[p] >> 16))
                                             + bfu((unsigned short)(ww[p] >> 16));
                    x = fmaf(fmaxf(av0, 0.f), s_v[c0], x);
                    x = fmaf(fmaxf(av1, 0.f), s_v[c0 + 1], x);
                }
            }
        }
    }
    // reduce partial scores over the 8 lanes of this k
    x += __shfl_xor(x, 1);
    x += __shfl_xor(x, 2);
    x += __shfl_xor(x, 4);
    if (cg == 0) s_a[k] = x;
    __syncthreads();

    // ---- softmax over K=32 (first 32 lanes of wave 0) ----
    if (t < 32) {
        float xi = s_a[t];
        float mx = xi;
        #pragma unroll
        for (int m = 16; m >= 1; m >>= 1) mx = fmaxf(mx, __shfl_xor(mx, m));
        float e = __expf(xi - mx);
        float s = e;
        #pragma unroll
        for (int m = 16; m >= 1; m >>= 1) s += __shfl_xor(s, m);
        s_a[t] = e / s;
    }
    __syncthreads();

    // ---- weighted gather: thread t owns output feature f = t ----
    float accv = 0.f;
    #pragma unroll 4
    for (int k2 = 0; k2 < KNBR; k2++) {
        int   j2 = s_j[k2];
        float ak = s_a[k2];
        if (j2) accv = fmaf(ak, ej[(size_t)(j2 - 1) * 256 + t], accv);
    }
    out[(size_t)n * 256 + t] = accv;
}

// ---------------------------------------------------------------------------
extern "C" void kernel_launch(void* const* d_in, const int* in_sizes, int n_in,
                              void* d_out, int out_size, void* d_ws, size_t ws_size,
                              hipStream_t stream)
{
    const float* ev = (const float*)d_in[0];
    const float* ej = (const float*)d_in[1];
    const float* ew = (const float*)d_in[2];
    const int*   vj = (const int*)d_in[3];
    const int*   vw = (const int*)d_in[4];
    const float* W1 = (const float*)d_in[5];   // [320][128]
    const float* W2 = (const float*)d_in[6];   // [256][128]
    const float* b  = (const float*)d_in[7];   // [128]
    const float* v  = (const float*)d_in[8];   // [128]
    float* out = (float*)d_out;

    const float* W1v = W1;               // rows 0..255
    const float* W1w = W1 + 256 * 128;   // rows 256..319

    const size_t rowsT = (size_t)M_ROWS + 1;
    const size_t needF = rowsT * 128 * sizeof(float) * 2 + (size_t)N_ROWS * 128 * sizeof(float);
    const size_t needH = rowsT * 128 * sizeof(__hip_bfloat16) * 2 + (size_t)N_ROWS * 128 * sizeof(float);

    const int gridTab = (M_ROWS + 63) / 64;
    const int gridEv  = (N_ROWS + 63) / 64;

    char* ws = (char*)d_ws;

    if (ws_size >= needF) {
        float* tabJ = (float*)ws;
        float* tabW = tabJ + rowsT * 128;
        float* evW1 = tabW + rowsT * 128;

        zero_row0<float><<<1, 128, 0, stream>>>(tabJ, tabW);
        gemm128<float, false><<<gridTab, 256, 0, stream>>>(ej, W2,  tabJ, nullptr, M_ROWS, INF,  1);
        gemm128<float, false><<<gridTab, 256, 0, stream>>>(ew, W1w, tabW, nullptr, M_ROWS, DIMW, 1);
        gemm128<float, true ><<<gridEv,  256, 0, stream>>>(ev, W1v, evW1, b,       N_ROWS, INF,  0);
        score_out<float><<<N_ROWS, 256, 0, stream>>>(tabJ, tabW, evW1, ej, vj, vw, v, out);
    } else if (ws_size >= needH) {
        __hip_bfloat16* tabJ = (__hip_bfloat16*)ws;
        __hip_bfloat16* tabW = tabJ + rowsT * 128;
        float*          evW1 = (float*)(tabW + rowsT * 128);

        zero_row0<__hip_bfloat16><<<1, 128, 0, stream>>>(tabJ, tabW);
        gemm128<__hip_bfloat16, false><<<gridTab, 256, 0, stream>>>(ej, W2,  tabJ, nullptr, M_ROWS, INF,  1);
        gemm128<__hip_bfloat16, false><<<gridTab, 256, 0, stream>>>(ew, W1w, tabW, nullptr, M_ROWS, DIMW, 1);
        gemm128<float, true ><<<gridEv, 256, 0, stream>>>(ev, W1v, evW1, b, N_ROWS, INF, 0);
        score_out<__hip_bfloat16><<<N_ROWS, 256, 0, stream>>>(tabJ, tabW, evW1, ej, vj, vw, v, out);
    }
    // else: workspace too small — nothing we can do without hipMalloc.
}

// Round 2
// 200.142 us; speedup vs baseline: 1.8241x; 1.8241x over previous
//
#include <hip/hip_runtime.h>
#include <hip/hip_bf16.h>
#include <type_traits>

#define N_ROWS 20000
#define KNBR   32
#define M_ROWS 100000
#define INF    256
#define DIMW   64

typedef __attribute__((ext_vector_type(8))) short short8v;
typedef __attribute__((ext_vector_type(4))) float f32x4;

// bf16 bits -> float (exact)
__device__ __forceinline__ float bfu(unsigned short s) {
    return __uint_as_float((unsigned)s << 16);
}
// f32 -> bf16 bits (RN)
__device__ __forceinline__ unsigned short f2b(float x) {
    union { __hip_bfloat16 h; unsigned short u; } cv;
    cv.h = __float2bfloat16(x);
    return cv.u;
}
__device__ __forceinline__ unsigned pk2(float a, float b) {
    return (unsigned)f2b(a) | ((unsigned)f2b(b) << 16);
}

// ---------------------------------------------------------------------------
// f32 vector GEMM (used only for the small evW1 = ev@W1[:256]+b, N=20000).
// ---------------------------------------------------------------------------
template <typename OutT, bool BIAS>
__global__ __launch_bounds__(256) void gemm128(
    const float* __restrict__ A, const float* __restrict__ W,
    OutT* __restrict__ out, const float* __restrict__ bias,
    int R, int F, int rowOffset)
{
    __shared__ float As[32][68];
    __shared__ float Ws[32][132];

    const int t  = threadIdx.x;
    const int m0 = blockIdx.x * 64;
    const int tx = t & 15;
    const int ty = t >> 4;

    float acc[4][8];
    #pragma unroll
    for (int i = 0; i < 4; i++)
        #pragma unroll
        for (int j = 0; j < 8; j++) acc[i][j] = 0.f;

    const int lrow = t >> 2;
    const int lkq  = t & 3;
    const int wrow = t >> 3;
    const int wc   = (t & 7) * 16;

    for (int k0 = 0; k0 < F; k0 += 32) {
        {
            int r = m0 + lrow;
            float4 a0 = make_float4(0.f, 0.f, 0.f, 0.f), a1 = a0;
            if (r < R) {
                const float* ap = A + (size_t)r * F + k0 + lkq * 8;
                a0 = *(const float4*)ap;
                a1 = *(const float4*)(ap + 4);
            }
            const int kb = lkq * 8;
            As[kb + 0][lrow] = a0.x; As[kb + 1][lrow] = a0.y;
            As[kb + 2][lrow] = a0.z; As[kb + 3][lrow] = a0.w;
            As[kb + 4][lrow] = a1.x; As[kb + 5][lrow] = a1.y;
            As[kb + 6][lrow] = a1.z; As[kb + 7][lrow] = a1.w;
        }
        {
            const float* wp = W + (size_t)(k0 + wrow) * 128 + wc;
            float4 w0 = *(const float4*)(wp + 0);
            float4 w1 = *(const float4*)(wp + 4);
            float4 w2 = *(const float4*)(wp + 8);
            float4 w3 = *(const float4*)(wp + 12);
            *(float4*)&Ws[wrow][wc + 0]  = w0;
            *(float4*)&Ws[wrow][wc + 4]  = w1;
            *(float4*)&Ws[wrow][wc + 8]  = w2;
            *(float4*)&Ws[wrow][wc + 12] = w3;
        }
        __syncthreads();

        #pragma unroll
        for (int kk = 0; kk < 32; kk++) {
            float4 av = *(const float4*)&As[kk][ty * 4];
            float4 w0 = *(const float4*)&Ws[kk][tx * 8];
            float4 w1 = *(const float4*)&Ws[kk][tx * 8 + 4];
            float a[4] = {av.x, av.y, av.z, av.w};
            float w[8] = {w0.x, w0.y, w0.z, w0.w, w1.x, w1.y, w1.z, w1.w};
            #pragma unroll
            for (int i = 0; i < 4; i++)
                #pragma unroll
                for (int j = 0; j < 8; j++)
                    acc[i][j] = fmaf(a[i], w[j], acc[i][j]);
        }
        __syncthreads();
    }

    #pragma unroll
    for (int i = 0; i < 4; i++) {
        int r = m0 + ty * 4 + i;
        if (r >= R) continue;
        OutT* op = out + (size_t)(r + rowOffset) * 128 + tx * 8;
        #pragma unroll
        for (int j = 0; j < 8; j++) {
            float vv = acc[i][j];
            if (BIAS) vv += bias[tx * 8 + j];
            if constexpr (std::is_same_v<OutT, float>) op[j] = vv;
            else op[j] = __float2bfloat16(vv);
        }
    }
}

// ---------------------------------------------------------------------------
// Prep: transpose+convert W2 -> WtJ[128][256] bf16, W1w -> WtW[128][64] bf16,
// and zero row 0 of both tables. Tiny.
// ---------------------------------------------------------------------------
__global__ void prep_wt(const float* __restrict__ W2, const float* __restrict__ W1w,
                        unsigned short* __restrict__ WtJ, unsigned short* __restrict__ WtW,
                        unsigned short* __restrict__ tabJ, unsigned short* __restrict__ tabW)
{
    int idx = blockIdx.x * 256 + threadIdx.x;
    const int total = 128 * 256 + 128 * 64;
    if (idx < total) {
        if (idx < 128 * 256) {
            int c = idx >> 8, k = idx & 255;
            WtJ[idx] = f2b(W2[k * 128 + c]);
        } else {
            int i2 = idx - 128 * 256;
            int c = i2 >> 6, k = i2 & 63;
            WtW[i2] = f2b(W1w[k * 128 + c]);
        }
    }
    if (idx < 128) { tabJ[idx] = 0; tabW[idx] = 0; }
}

// ---------------------------------------------------------------------------
// MFMA GEMM: out[(r+1)][0..127] = bf16(A[r][:]) @ bf16(W[:][:])  (f32 acc)
// A: [R][F] f32.  Wt: [128][F] bf16 (pre-transposed).  outB: [(R+1)][128] bf16.
// Optionally writes Ah = bf16(A) (fused cast, elements staged exactly once).
// Tile 64x128, BK=64, 4 waves; mfma_f32_16x16x32_bf16; XOR-swizzled LDS.
// A-frag: lane l holds A[l&15][(l>>4)*8 + i]; B-frag: W[k][ct*16 + (l&15)]
// via Wt rows; C/D: col = l&15, row = (l>>4)*4 + reg  [learn_hip m89].
// ---------------------------------------------------------------------------
template <int F, bool WRITE_AH>
__global__ __launch_bounds__(256) void mfma_gemm(
    const float* __restrict__ A, const unsigned short* __restrict__ Wt,
    unsigned short* __restrict__ outB, unsigned short* __restrict__ Ah, int R)
{
    __shared__ __align__(16) unsigned short As[64 * 64];      // swizzled [row][64]
    __shared__ __align__(16) unsigned short Ws[128 * 64];     // swizzled [col][64]
    __shared__ __align__(16) unsigned short Tile[4][16 * 136];

    const int t   = threadIdx.x;
    const int m0  = blockIdx.x * 64;
    const int wid = t >> 6;
    const int l   = t & 63;
    const int l15 = l & 15;
    const int l4  = l >> 4;

    f32x4 acc[8];
    #pragma unroll
    for (int ct = 0; ct < 8; ct++) acc[ct] = (f32x4){0.f, 0.f, 0.f, 0.f};

    const int ar = t >> 2;            // A row 0..63
    const int ac = (t & 3) * 16;      // 16 f32 per thread
    const int wr = t >> 1;            // Wt row (W col) 0..127
    const int wc = (t & 1) * 32;      // 32 bf16 per thread

    for (int k0 = 0; k0 < F; k0 += 64) {
        // ---- stage A (f32 -> bf16), fused Ah write ----
        {
            int r = m0 + ar;
            unsigned pk[8];
            if (r < R) {
                const float* ap = A + (size_t)r * F + k0 + ac;
                #pragma unroll
                for (int q = 0; q < 4; q++) {
                    float4 f = *(const float4*)(ap + q * 4);
                    pk[q * 2 + 0] = pk2(f.x, f.y);
                    pk[q * 2 + 1] = pk2(f.z, f.w);
                }
                if (WRITE_AH) {
                    uint4 lo = {pk[0], pk[1], pk[2], pk[3]};
                    uint4 hi = {pk[4], pk[5], pk[6], pk[7]};
                    *(uint4*)(Ah + (size_t)r * F + k0 + ac)     = lo;
                    *(uint4*)(Ah + (size_t)r * F + k0 + ac + 8) = hi;
                }
            } else {
                #pragma unroll
                for (int q = 0; q < 8; q++) pk[q] = 0u;
            }
            int base = ar * 128 + ac * 2;       // bytes
            int swz  = (ar & 7) << 4;
            uint4 lo = {pk[0], pk[1], pk[2], pk[3]};
            uint4 hi = {pk[4], pk[5], pk[6], pk[7]};
            *(uint4*)((char*)As + ((base)      ^ swz)) = lo;
            *(uint4*)((char*)As + ((base + 16) ^ swz)) = hi;
        }
        // ---- stage Wt (bf16 copy) ----
        {
            const unsigned short* wp = Wt + (size_t)wr * F + k0 + wc;
            int base = wr * 128 + wc * 2;
            int swz  = (wr & 7) << 4;
            #pragma unroll
            for (int q = 0; q < 4; q++) {
                uint4 wv = *(const uint4*)(wp + q * 8);
                *(uint4*)((char*)Ws + ((base + q * 16) ^ swz)) = wv;
            }
        }
        __syncthreads();

        // ---- MFMA ----
        const int arow = wid * 16 + l15;
        const int aswz = (arow & 7) << 4;
        short8v afrag[2];
        #pragma unroll
        for (int ks = 0; ks < 2; ks++) {
            int boff = arow * 128 + (ks * 32 + l4 * 8) * 2;
            afrag[ks] = *(const short8v*)((const char*)As + (boff ^ aswz));
        }
        #pragma unroll
        for (int ct = 0; ct < 8; ct++) {
            int bcol = ct * 16 + l15;
            int bswz = (bcol & 7) << 4;
            #pragma unroll
            for (int ks = 0; ks < 2; ks++) {
                int boff = bcol * 128 + (ks * 32 + l4 * 8) * 2;
                short8v bfrag = *(const short8v*)((const char*)Ws + (boff ^ bswz));
                acc[ct] = __builtin_amdgcn_mfma_f32_16x16x32_bf16(afrag[ks], bfrag, acc[ct], 0, 0, 0);
            }
        }
        __syncthreads();
    }

    // ---- repack through LDS, coalesced bf16 store ----
    #pragma unroll
    for (int ct = 0; ct < 8; ct++)
        #pragma unroll
        for (int i = 0; i < 4; i++)
            Tile[wid][(l4 * 4 + i) * 136 + ct * 16 + l15] = f2b(acc[ct][i]);
    __syncthreads();
    {
        int row = l >> 2, part = l & 3;
        int gr = m0 + wid * 16 + row;
        if (gr < R) {
            unsigned short* op = outB + (size_t)(gr + 1) * 128 + part * 32;
            const unsigned short* tp = &Tile[wid][row * 136 + part * 32];
            #pragma unroll
            for (int q = 0; q < 4; q++)
                *(uint4*)(op + q * 8) = *(const uint4*)(tp + q * 8);
        }
    }
}

// ---------------------------------------------------------------------------
// Fused score + softmax + weighted gather (all-bf16 gather set).
// ---------------------------------------------------------------------------
__global__ __launch_bounds__(256) void score_out(
    const unsigned short* __restrict__ tabJ, const unsigned short* __restrict__ tabW,
    const unsigned short* __restrict__ evW1, const unsigned short* __restrict__ ejh,
    const int* __restrict__ vj, const int* __restrict__ vw,
    const float* __restrict__ vvec, float* __restrict__ out)
{
    const int n = blockIdx.x;
    const int t = threadIdx.x;

    __shared__ float  s_ev[128];
    __shared__ float  s_v[128];
    __shared__ int    s_j[32];
    __shared__ int    s_w[32];
    __shared__ float  s_a[32];
    __shared__ float2 s_red[2][128];

    if (t < 128) {
        s_ev[t] = bfu(evW1[(size_t)n * 128 + t]);
        s_v[t]  = vvec[t];
    } else if (t < 160) {
        int k = t - 128;
        s_j[k] = vj[n * KNBR + k];
        s_w[k] = vw[n * KNBR + k];
    }
    __syncthreads();

    // ---- scores: thread t -> neighbor k = t>>3, 16 channels ----
    const int k  = t >> 3;
    const int cg = t & 7;
    const int j  = s_j[k];
    const int w  = s_w[k];

    float x = 0.f;
    {
        const uint4* tj4 = (const uint4*)(tabJ + (size_t)j * 128 + cg * 16);
        const uint4* tw4 = (const uint4*)(tabW + (size_t)w * 128 + cg * 16);
        #pragma unroll
        for (int q = 0; q < 2; q++) {
            uint4 ja = tj4[q], wa = tw4[q];
            unsigned jw[4] = {ja.x, ja.y, ja.z, ja.w};
            unsigned ww[4] = {wa.x, wa.y, wa.z, wa.w};
            #pragma unroll
            for (int p = 0; p < 4; p++) {
                int c0 = cg * 16 + q * 8 + p * 2;
                float av0 = s_ev[c0]     + bfu((unsigned short)(jw[p] & 0xffff))
                                         + bfu((unsigned short)(ww[p] & 0xffff));
                float av1 = s_ev[c0 + 1] + bfu((unsigned short)(jw[p] >> 16))
                                         + bfu((unsigned short)(ww[p] >> 16));
                x = fmaf(fmaxf(av0, 0.f), s_v[c0], x);
                x = fmaf(fmaxf(av1, 0.f), s_v[c0 + 1], x);
            }
        }
    }
    x += __shfl_xor(x, 1);
    x += __shfl_xor(x, 2);
    x += __shfl_xor(x, 4);
    if (cg == 0) s_a[k] = x;
    __syncthreads();

    // ---- softmax over K=32 ----
    if (t < 32) {
        float xi = s_a[t];
        float mx = xi;
        #pragma unroll
        for (int m = 16; m >= 1; m >>= 1) mx = fmaxf(mx, __shfl_xor(mx, m));
        float e = __expf(xi - mx);
        float s = e;
        #pragma unroll
        for (int m = 16; m >= 1; m >>= 1) s += __shfl_xor(s, m);
        s_a[t] = e / s;
    }
    __syncthreads();

    // ---- weighted gather from bf16 ejh: thread owns feature pair p, k-half h
    const int p = t & 127;
    const int h = t >> 7;
    float2 accv = {0.f, 0.f};
    #pragma unroll 4
    for (int kk = 0; kk < 16; kk++) {
        int k2 = h * 16 + kk;
        int j2 = s_j[k2];
        if (j2) {
            unsigned u = *(const unsigned*)(ejh + (size_t)(j2 - 1) * 256 + p * 2);
            float ak = s_a[k2];
            accv.x = fmaf(ak, bfu((unsigned short)(u & 0xffff)), accv.x);
            accv.y = fmaf(ak, bfu((unsigned short)(u >> 16)),    accv.y);
        }
    }
    s_red[h][p] = accv;
    __syncthreads();
    if (t < 128) {
        float2 a0 = s_red[0][t], a1 = s_red[1][t];
        float2 r = {a0.x + a1.x, a0.y + a1.y};
        *(float2*)(out + (size_t)n * 256 + t * 2) = r;
    }
}

// ---------------------------------------------------------------------------
extern "C" void kernel_launch(void* const* d_in, const int* in_sizes, int n_in,
                              void* d_out, int out_size, void* d_ws, size_t ws_size,
                              hipStream_t stream)
{
    const float* ev = (const float*)d_in[0];
    const float* ej = (const float*)d_in[1];
    const float* ew = (const float*)d_in[2];
    const int*   vj = (const int*)d_in[3];
    const int*   vw = (const int*)d_in[4];
    const float* W1 = (const float*)d_in[5];   // [320][128]
    const float* W2 = (const float*)d_in[6];   // [256][128]
    const float* b  = (const float*)d_in[7];   // [128]
    const float* v  = (const float*)d_in[8];   // [128]
    float* out = (float*)d_out;

    const float* W1w = W1 + 256 * 128;         // rows 256..319

    // workspace layout (all bf16 except noted): ~107.7 MB
    unsigned short* tabJ = (unsigned short*)d_ws;                      // (M+1)*128
    unsigned short* tabW = tabJ + (size_t)(M_ROWS + 1) * 128;          // (M+1)*128
    unsigned short* ejh  = tabW + (size_t)(M_ROWS + 1) * 128;          // M*256
    unsigned short* evW1 = ejh  + (size_t)M_ROWS * 256;                // N*128
    unsigned short* WtJ  = evW1 + (size_t)N_ROWS * 128;                // 128*256
    unsigned short* WtW  = WtJ  + 128 * 256;                           // 128*64

    const int gridTab = (M_ROWS + 63) / 64;
    const int gridEv  = (N_ROWS + 63) / 64;

    prep_wt<<<160, 256, 0, stream>>>(W2, W1w, WtJ, WtW, tabJ, tabW);
    mfma_gemm<INF,  true ><<<gridTab, 256, 0, stream>>>(ej, WtJ, tabJ, ejh,     M_ROWS);
    mfma_gemm<DIMW, false><<<gridTab, 256, 0, stream>>>(ew, WtW, tabW, nullptr, M_ROWS);
    gemm128<__hip_bfloat16, true><<<gridEv, 256, 0, stream>>>(ev, W1, (__hip_bfloat16*)evW1, b, N_ROWS, INF, 0);
    score_out<<<N_ROWS, 256, 0, stream>>>(tabJ, tabW, evW1, ejh, vj, vw, v, out);
}

// Round 4
// 191.586 us; speedup vs baseline: 1.9056x; 1.0447x over previous
//
#include <hip/hip_runtime.h>
#include <hip/hip_bf16.h>
#include <type_traits>

#define N_ROWS 20000
#define KNBR   32
#define M_ROWS 100000
#define INF    256
#define DIMW   64

typedef __attribute__((ext_vector_type(8))) short short8v;
typedef __attribute__((ext_vector_type(4))) float f32x4;
typedef __attribute__((ext_vector_type(2))) float f32x2;

// bf16 bits -> float (exact)
__device__ __forceinline__ float bfu(unsigned short s) {
    return __uint_as_float((unsigned)s << 16);
}
// f32 -> bf16 bits (RN)
__device__ __forceinline__ unsigned short f2b(float x) {
    union { __hip_bfloat16 h; unsigned short u; } cv;
    cv.h = __float2bfloat16(x);
    return cv.u;
}
__device__ __forceinline__ unsigned pk2(float a, float b) {
    return (unsigned)f2b(a) | ((unsigned)f2b(b) << 16);
}

// ---------------------------------------------------------------------------
// Prep: transpose+convert weights to bf16 [col][k] layout; zero table row 0.
//   WtJ[128][256] <- W2, WtW[128][64] <- W1 rows 256..319, WtV[128][256] <- W1 rows 0..255
// ---------------------------------------------------------------------------
__global__ void prep_wt(const float* __restrict__ W2, const float* __restrict__ W1w,
                        const float* __restrict__ W1v,
                        unsigned short* __restrict__ WtJ, unsigned short* __restrict__ WtW,
                        unsigned short* __restrict__ WtV,
                        unsigned short* __restrict__ tabJ, unsigned short* __restrict__ tabW)
{
    int idx = blockIdx.x * 256 + threadIdx.x;
    if (idx < 128 * 256) {
        int c = idx >> 8, k = idx & 255;
        WtJ[idx] = f2b(W2[k * 128 + c]);
    } else if (idx < 128 * 256 + 128 * 64) {
        int i2 = idx - 128 * 256;
        int c = i2 >> 6, k = i2 & 63;
        WtW[i2] = f2b(W1w[k * 128 + c]);
    } else if (idx < 2 * 128 * 256 + 128 * 64) {
        int i3 = idx - (128 * 256 + 128 * 64);
        int c = i3 >> 8, k = i3 & 255;
        WtV[i3] = f2b(W1v[k * 128 + c]);
    }
    if (idx < 128) { tabJ[idx] = 0; tabW[idx] = 0; }
}

// ---------------------------------------------------------------------------
// MFMA GEMM: out[(r+rowOffset)][0..127] = bf16(A[r][:]) @ W (+bias), f32 acc.
// A: [R][F] f32 (streamed, non-temporal). Wt: [128][F] bf16 pre-transposed.
// outB: bf16 [.][128]. Optional fused Ah = bf16(A).
// Tile 64x128, BK=64, 4 waves; mfma_f32_16x16x32_bf16; XOR-swizzled LDS.
// C/D layout: col = l&15, row = (l>>4)*4 + reg  [learn_hip m89].
// ---------------------------------------------------------------------------
template <int F, bool WRITE_AH, bool BIAS>
__global__ __launch_bounds__(256) void mfma_gemm(
    const float* __restrict__ A, const unsigned short* __restrict__ Wt,
    unsigned short* __restrict__ outB, unsigned short* __restrict__ Ah,
    const float* __restrict__ bias, int R, int rowOffset)
{
    __shared__ __align__(16) unsigned short As[64 * 64];      // swizzled [row][64]
    __shared__ __align__(16) unsigned short Ws[128 * 64];     // swizzled [col][64]
    __shared__ __align__(16) unsigned short Tile[4][16 * 136];

    const int t   = threadIdx.x;
    const int m0  = blockIdx.x * 64;
    const int wid = t >> 6;
    const int l   = t & 63;
    const int l15 = l & 15;
    const int l4  = l >> 4;

    f32x4 acc[8];
    #pragma unroll
    for (int ct = 0; ct < 8; ct++) acc[ct] = (f32x4){0.f, 0.f, 0.f, 0.f};

    const int ar = t >> 2;            // A row 0..63
    const int ac = (t & 3) * 16;      // 16 f32 per thread
    const int wr = t >> 1;            // Wt row (W col) 0..127
    const int wc = (t & 1) * 32;      // 32 bf16 per thread

    for (int k0 = 0; k0 < F; k0 += 64) {
        // ---- stage A (f32 -> bf16), fused Ah write ----
        {
            int r = m0 + ar;
            unsigned pk[8];
            if (r < R) {
                const float* ap = A + (size_t)r * F + k0 + ac;
                #pragma unroll
                for (int q = 0; q < 4; q++) {
                    f32x4 f = __builtin_nontemporal_load((const f32x4*)(ap + q * 4));
                    pk[q * 2 + 0] = pk2(f.x, f.y);
                    pk[q * 2 + 1] = pk2(f.z, f.w);
                }
                if (WRITE_AH) {
                    uint4 lo = {pk[0], pk[1], pk[2], pk[3]};
                    uint4 hi = {pk[4], pk[5], pk[6], pk[7]};
                    *(uint4*)(Ah + (size_t)r * F + k0 + ac)     = lo;
                    *(uint4*)(Ah + (size_t)r * F + k0 + ac + 8) = hi;
                }
            } else {
                #pragma unroll
                for (int q = 0; q < 8; q++) pk[q] = 0u;
            }
            int base = ar * 128 + ac * 2;       // bytes
            int swz  = (ar & 7) << 4;
            uint4 lo = {pk[0], pk[1], pk[2], pk[3]};
            uint4 hi = {pk[4], pk[5], pk[6], pk[7]};
            *(uint4*)((char*)As + ((base)      ^ swz)) = lo;
            *(uint4*)((char*)As + ((base + 16) ^ swz)) = hi;
        }
        // ---- stage Wt (bf16 copy) ----
        {
            const unsigned short* wp = Wt + (size_t)wr * F + k0 + wc;
            int base = wr * 128 + wc * 2;
            int swz  = (wr & 7) << 4;
            #pragma unroll
            for (int q = 0; q < 4; q++) {
                uint4 wv = *(const uint4*)(wp + q * 8);
                *(uint4*)((char*)Ws + ((base + q * 16) ^ swz)) = wv;
            }
        }
        __syncthreads();

        // ---- MFMA ----
        const int arow = wid * 16 + l15;
        const int aswz = (arow & 7) << 4;
        short8v afrag[2];
        #pragma unroll
        for (int ks = 0; ks < 2; ks++) {
            int boff = arow * 128 + (ks * 32 + l4 * 8) * 2;
            afrag[ks] = *(const short8v*)((const char*)As + (boff ^ aswz));
        }
        #pragma unroll
        for (int ct = 0; ct < 8; ct++) {
            int bcol = ct * 16 + l15;
            int bswz = (bcol & 7) << 4;
            #pragma unroll
            for (int ks = 0; ks < 2; ks++) {
                int boff = bcol * 128 + (ks * 32 + l4 * 8) * 2;
                short8v bfrag = *(const short8v*)((const char*)Ws + (boff ^ bswz));
                acc[ct] = __builtin_amdgcn_mfma_f32_16x16x32_bf16(afrag[ks], bfrag, acc[ct], 0, 0, 0);
            }
        }
        __syncthreads();
    }

    // ---- repack through LDS (+bias), coalesced bf16 store ----
    #pragma unroll
    for (int ct = 0; ct < 8; ct++) {
        float bb = BIAS ? bias[ct * 16 + l15] : 0.f;
        #pragma unroll
        for (int i = 0; i < 4; i++)
            Tile[wid][(l4 * 4 + i) * 136 + ct * 16 + l15] = f2b(acc[ct][i] + bb);
    }
    __syncthreads();
    {
        int row = l >> 2, part = l & 3;
        int gr = m0 + wid * 16 + row;
        if (gr < R) {
            unsigned short* op = outB + (size_t)(gr + rowOffset) * 128 + part * 32;
            const unsigned short* tp = &Tile[wid][row * 136 + part * 32];
            #pragma unroll
            for (int q = 0; q < 4; q++)
                *(uint4*)(op + q * 8) = *(const uint4*)(tp + q * 8);
        }
    }
}

// ---------------------------------------------------------------------------
// Fused score + softmax + weighted gather (all-bf16 gather set).
// ---------------------------------------------------------------------------
__global__ __launch_bounds__(256) void score_out(
    const unsigned short* __restrict__ tabJ, const unsigned short* __restrict__ tabW,
    const unsigned short* __restrict__ evW1, const unsigned short* __restrict__ ejh,
    const int* __restrict__ vj, const int* __restrict__ vw,
    const float* __restrict__ vvec, float* __restrict__ out)
{
    const int n = blockIdx.x;
    const int t = threadIdx.x;

    __shared__ float  s_ev[128];
    __shared__ float  s_v[128];
    __shared__ int    s_j[32];
    __shared__ int    s_w[32];
    __shared__ float  s_a[32];
    __shared__ float2 s_red[2][128];

    if (t < 128) {
        s_ev[t] = bfu(evW1[(size_t)n * 128 + t]);
        s_v[t]  = vvec[t];
    } else if (t < 160) {
        int k = t - 128;
        s_j[k] = vj[n * KNBR + k];
        s_w[k] = vw[n * KNBR + k];
    }
    __syncthreads();

    // ---- scores: thread t -> neighbor k = t>>3, 16 channels ----
    const int k  = t >> 3;
    const int cg = t & 7;
    const int j  = s_j[k];
    const int w  = s_w[k];

    float x = 0.f;
    {
        const uint4* tj4 = (const uint4*)(tabJ + (size_t)j * 128 + cg * 16);
        const uint4* tw4 = (const uint4*)(tabW + (size_t)w * 128 + cg * 16);
        uint4 ja0 = tj4[0], ja1 = tj4[1];          // issue all 4 loads first
        uint4 wa0 = tw4[0], wa1 = tw4[1];
        unsigned jw[8] = {ja0.x, ja0.y, ja0.z, ja0.w, ja1.x, ja1.y, ja1.z, ja1.w};
        unsigned ww[8] = {wa0.x, wa0.y, wa0.z, wa0.w, wa1.x, wa1.y, wa1.z, wa1.w};
        #pragma unroll
        for (int p = 0; p < 8; p++) {
            int c0 = cg * 16 + p * 2;
            float av0 = s_ev[c0]     + bfu((unsigned short)(jw[p] & 0xffff))
                                     + bfu((unsigned short)(ww[p] & 0xffff));
            float av1 = s_ev[c0 + 1] + bfu((unsigned short)(jw[p] >> 16))
                                     + bfu((unsigned short)(ww[p] >> 16));
            x = fmaf(fmaxf(av0, 0.f), s_v[c0], x);
            x = fmaf(fmaxf(av1, 0.f), s_v[c0 + 1], x);
        }
    }
    x += __shfl_xor(x, 1);
    x += __shfl_xor(x, 2);
    x += __shfl_xor(x, 4);
    if (cg == 0) s_a[k] = x;
    __syncthreads();

    // ---- softmax over K=32 ----
    if (t < 32) {
        float xi = s_a[t];
        float mx = xi;
        #pragma unroll
        for (int m = 16; m >= 1; m >>= 1) mx = fmaxf(mx, __shfl_xor(mx, m));
        float e = __expf(xi - mx);
        float s = e;
        #pragma unroll
        for (int m = 16; m >= 1; m >>= 1) s += __shfl_xor(s, m);
        s_a[t] = e / s;
    }
    __syncthreads();

    // ---- weighted gather: thread owns feature pair p, k-half h ----
    const int p = t & 127;
    const int h = t >> 7;
    unsigned uu[16];
    float    aa[16];
    #pragma unroll
    for (int kk = 0; kk < 16; kk++) {          // issue all 16 loads first
        int k2 = h * 16 + kk;
        int j2 = s_j[k2];
        aa[kk] = s_a[k2];
        uu[kk] = j2 ? *(const unsigned*)(ejh + (size_t)(j2 - 1) * 256 + p * 2) : 0u;
    }
    float2 accv = {0.f, 0.f};
    #pragma unroll
    for (int kk = 0; kk < 16; kk++) {
        accv.x = fmaf(aa[kk], bfu((unsigned short)(uu[kk] & 0xffff)), accv.x);
        accv.y = fmaf(aa[kk], bfu((unsigned short)(uu[kk] >> 16)),    accv.y);
    }
    s_red[h][p] = accv;
    __syncthreads();
    if (t < 128) {
        float2 a0 = s_red[0][t], a1 = s_red[1][t];
        f32x2 r = {a0.x + a1.x, a0.y + a1.y};
        __builtin_nontemporal_store(r, (f32x2*)(out + (size_t)n * 256 + t * 2));
    }
}

// ---------------------------------------------------------------------------
extern "C" void kernel_launch(void* const* d_in, const int* in_sizes, int n_in,
                              void* d_out, int out_size, void* d_ws, size_t ws_size,
                              hipStream_t stream)
{
    const float* ev = (const float*)d_in[0];
    const float* ej = (const float*)d_in[1];
    const float* ew = (const float*)d_in[2];
    const int*   vj = (const int*)d_in[3];
    const int*   vw = (const int*)d_in[4];
    const float* W1 = (const float*)d_in[5];   // [320][128]
    const float* W2 = (const float*)d_in[6];   // [256][128]
    const float* b  = (const float*)d_in[7];   // [128]
    const float* v  = (const float*)d_in[8];   // [128]
    float* out = (float*)d_out;

    const float* W1v = W1;                     // rows 0..255
    const float* W1w = W1 + 256 * 128;         // rows 256..319

    // workspace layout (bf16), ~107.8 MB
    unsigned short* tabJ = (unsigned short*)d_ws;                      // (M+1)*128
    unsigned short* tabW = tabJ + (size_t)(M_ROWS + 1) * 128;          // (M+1)*128
    unsigned short* ejh  = tabW + (size_t)(M_ROWS + 1) * 128;          // M*256
    unsigned short* evW1 = ejh  + (size_t)M_ROWS * 256;                // N*128
    unsigned short* WtJ  = evW1 + (size_t)N_ROWS * 128;                // 128*256
    unsigned short* WtW  = WtJ  + 128 * 256;                           // 128*64
    unsigned short* WtV  = WtW  + 128 * 64;                            // 128*256

    const int gridTab = (M_ROWS + 63) / 64;
    const int gridEv  = (N_ROWS + 63) / 64;

    prep_wt<<<288, 256, 0, stream>>>(W2, W1w, W1v, WtJ, WtW, WtV, tabJ, tabW);
    mfma_gemm<INF,  true,  false><<<gridTab, 256, 0, stream>>>(ej, WtJ, tabJ, ejh,     nullptr, M_ROWS, 1);
    mfma_gemm<DIMW, false, false><<<gridTab, 256, 0, stream>>>(ew, WtW, tabW, nullptr, nullptr, M_ROWS, 1);
    mfma_gemm<INF,  false, true ><<<gridEv,  256, 0, stream>>>(ev, WtV, evW1, nullptr, b,       N_ROWS, 0);
    score_out<<<N_ROWS, 256, 0, stream>>>(tabJ, tabW, evW1, ejh, vj, vw, v, out);
}

// Round 5
// 148.229 us; speedup vs baseline: 2.4629x; 1.2925x over previous
//
#include <hip/hip_runtime.h>
#include <hip/hip_bf16.h>
#include <type_traits>

#define N_ROWS 20000
#define KNBR   32
#define M_ROWS 100000
#define INF    256
#define DIMW   64

#define GRID_J ((M_ROWS + 63) / 64)   // 1563
#define GRID_V ((N_ROWS + 63) / 64)   // 313

typedef __attribute__((ext_vector_type(8))) short short8v;
typedef __attribute__((ext_vector_type(4))) float f32x4;
typedef __attribute__((ext_vector_type(2))) float f32x2;

// bf16 bits -> float (exact)
__device__ __forceinline__ float bfu(unsigned short s) {
    return __uint_as_float((unsigned)s << 16);
}
// f32 -> bf16 bits (RN)
__device__ __forceinline__ unsigned short f2b(float x) {
    union { __hip_bfloat16 h; unsigned short u; } cv;
    cv.h = __float2bfloat16(x);
    return cv.u;
}
__device__ __forceinline__ unsigned pk2(float a, float b) {
    return (unsigned)f2b(a) | ((unsigned)f2b(b) << 16);
}

// ---------------------------------------------------------------------------
// Prep: transpose+convert weights to bf16 [col][k] layout; zero table row 0.
// ---------------------------------------------------------------------------
__global__ void prep_wt(const float* __restrict__ W2, const float* __restrict__ W1w,
                        const float* __restrict__ W1v,
                        unsigned short* __restrict__ WtJ, unsigned short* __restrict__ WtW,
                        unsigned short* __restrict__ WtV,
                        unsigned short* __restrict__ tabJ, unsigned short* __restrict__ tabW)
{
    int idx = blockIdx.x * 256 + threadIdx.x;
    if (idx < 128 * 256) {
        int c = idx >> 8, k = idx & 255;
        WtJ[idx] = f2b(W2[k * 128 + c]);
    } else if (idx < 128 * 256 + 128 * 64) {
        int i2 = idx - 128 * 256;
        int c = i2 >> 6, k = i2 & 63;
        WtW[i2] = f2b(W1w[k * 128 + c]);
    } else if (idx < 2 * 128 * 256 + 128 * 64) {
        int i3 = idx - (128 * 256 + 128 * 64);
        int c = i3 >> 8, k = i3 & 255;
        WtV[i3] = f2b(W1v[k * 128 + c]);
    }
    if (idx < 128) { tabJ[idx] = 0; tabW[idx] = 0; }
}

// ---------------------------------------------------------------------------
// GEMM body (device fn): out[(r+rowOffset)][0..127] = bf16(A[r][:]) @ W (+bias)
// Tile 64 rows x 128 cols, BK=64; 4 waves in 2x2 (each 32 rows x 64 cols):
// per K-step per wave: 4 A-frag + 8 B-frag ds_read_b128, 16 MFMA.
// C/D layout: col = l&15, row = (l>>4)*4 + reg  [learn_hip m89].
// ---------------------------------------------------------------------------
template <int F, bool WRITE_AH, bool BIAS>
__device__ __forceinline__ void gemm_body(
    const float* __restrict__ A, const unsigned short* __restrict__ Wt,
    unsigned short* __restrict__ outB, unsigned short* __restrict__ Ah,
    const float* __restrict__ bias, int R, int rowOffset, int m0,
    unsigned short* __restrict__ As,    // [64][64] swizzled bf16
    unsigned short* __restrict__ Ws,    // [128][64] swizzled bf16
    unsigned short* __restrict__ Tile)  // [64][136] bf16
{
    const int t   = threadIdx.x;
    const int wid = t >> 6;
    const int l   = t & 63;
    const int l15 = l & 15;
    const int l4  = l >> 4;
    const int wr  = wid >> 1;          // 0..1: row half
    const int wc  = wid & 1;           // 0..1: col half

    f32x4 acc[2][4];
    #pragma unroll
    for (int rg = 0; rg < 2; rg++)
        #pragma unroll
        for (int ct = 0; ct < 4; ct++) acc[rg][ct] = (f32x4){0.f, 0.f, 0.f, 0.f};

    const int ar  = t >> 2;            // A row 0..63
    const int ac  = (t & 3) * 16;      // 16 f32 per thread
    const int wrS = t >> 1;            // Wt row (W col) 0..127
    const int wcS = (t & 1) * 32;      // 32 bf16 per thread

    for (int k0 = 0; k0 < F; k0 += 64) {
        // ---- stage A (f32 -> bf16), fused Ah write ----
        {
            int r = m0 + ar;
            unsigned pk[8];
            if (r < R) {
                const float* ap = A + (size_t)r * F + k0 + ac;
                #pragma unroll
                for (int q = 0; q < 4; q++) {
                    f32x4 f = *(const f32x4*)(ap + q * 4);
                    pk[q * 2 + 0] = pk2(f.x, f.y);
                    pk[q * 2 + 1] = pk2(f.z, f.w);
                }
                if (WRITE_AH) {
                    uint4 lo = {pk[0], pk[1], pk[2], pk[3]};
                    uint4 hi = {pk[4], pk[5], pk[6], pk[7]};
                    *(uint4*)(Ah + (size_t)r * F + k0 + ac)     = lo;
                    *(uint4*)(Ah + (size_t)r * F + k0 + ac + 8) = hi;
                }
            } else {
                #pragma unroll
                for (int q = 0; q < 8; q++) pk[q] = 0u;
            }
            int base = ar * 128 + ac * 2;       // bytes
            int swz  = (ar & 7) << 4;
            uint4 lo = {pk[0], pk[1], pk[2], pk[3]};
            uint4 hi = {pk[4], pk[5], pk[6], pk[7]};
            *(uint4*)((char*)As + ((base)      ^ swz)) = lo;
            *(uint4*)((char*)As + ((base + 16) ^ swz)) = hi;
        }
        // ---- stage Wt ----
        {
            const unsigned short* wp = Wt + (size_t)wrS * F + k0 + wcS;
            int base = wrS * 128 + wcS * 2;
            int swz  = (wrS & 7) << 4;
            #pragma unroll
            for (int q = 0; q < 4; q++) {
                uint4 wv = *(const uint4*)(wp + q * 8);
                *(uint4*)((char*)Ws + ((base + q * 16) ^ swz)) = wv;
            }
        }
        __syncthreads();

        // ---- MFMA ----
        short8v afrag[2][2];
        #pragma unroll
        for (int rg = 0; rg < 2; rg++) {
            int arow = wr * 32 + rg * 16 + l15;
            int aswz = (arow & 7) << 4;
            #pragma unroll
            for (int ks = 0; ks < 2; ks++) {
                int boff = arow * 128 + (ks * 32 + l4 * 8) * 2;
                afrag[rg][ks] = *(const short8v*)((const char*)As + (boff ^ aswz));
            }
        }
        #pragma unroll
        for (int ct = 0; ct < 4; ct++) {
            int bcol = wc * 64 + ct * 16 + l15;
            int bswz = (bcol & 7) << 4;
            #pragma unroll
            for (int ks = 0; ks < 2; ks++) {
                int boff = bcol * 128 + (ks * 32 + l4 * 8) * 2;
                short8v bfrag = *(const short8v*)((const char*)Ws + (boff ^ bswz));
                #pragma unroll
                for (int rg = 0; rg < 2; rg++)
                    acc[rg][ct] = __builtin_amdgcn_mfma_f32_16x16x32_bf16(afrag[rg][ks], bfrag, acc[rg][ct], 0, 0, 0);
            }
        }
        __syncthreads();
    }

    // ---- repack through LDS (+bias), coalesced bf16 store ----
    #pragma unroll
    for (int rg = 0; rg < 2; rg++)
        #pragma unroll
        for (int ct = 0; ct < 4; ct++) {
            int col = wc * 64 + ct * 16 + l15;
            float bb = BIAS ? bias[col] : 0.f;
            #pragma unroll
            for (int i = 0; i < 4; i++)
                Tile[(wr * 32 + rg * 16 + l4 * 4 + i) * 136 + col] = f2b(acc[rg][ct][i] + bb);
        }
    __syncthreads();
    {
        int row = t >> 2, part = t & 3;
        int gr = m0 + row;
        if (gr < R) {
            unsigned short* op = outB + (size_t)(gr + rowOffset) * 128 + part * 32;
            const unsigned short* tp = Tile + row * 136 + part * 32;
            #pragma unroll
            for (int q = 0; q < 4; q++)
                *(uint4*)(op + q * 8) = *(const uint4*)(tp + q * 8);
        }
    }
    __syncthreads();
}

// ---------------------------------------------------------------------------
// One fused kernel for all three table GEMMs.
// Blocks [0, GRID_J): rows of ej -> tabJ + ejh, then rows of ew -> tabW.
// Blocks [GRID_J, GRID_J+GRID_V): rows of ev -> evW1 (+bias).
// ---------------------------------------------------------------------------
__global__ __launch_bounds__(256) void tables_fused(
    const float* __restrict__ ej, const float* __restrict__ ew,
    const float* __restrict__ ev,
    const unsigned short* __restrict__ WtJ, const unsigned short* __restrict__ WtW,
    const unsigned short* __restrict__ WtV,
    unsigned short* __restrict__ tabJ, unsigned short* __restrict__ tabW,
    unsigned short* __restrict__ evW1, unsigned short* __restrict__ ejh,
    const float* __restrict__ bias)
{
    __shared__ __align__(16) unsigned short As[64 * 64];
    __shared__ __align__(16) unsigned short Ws[128 * 64];
    __shared__ __align__(16) unsigned short Tile[64 * 136];

    const int bid = blockIdx.x;
    if (bid < GRID_J) {
        const int m0 = bid * 64;
        gemm_body<INF,  true,  false>(ej, WtJ, tabJ, ejh,     nullptr, M_ROWS, 1, m0, As, Ws, Tile);
        gemm_body<DIMW, false, false>(ew, WtW, tabW, nullptr, nullptr, M_ROWS, 1, m0, As, Ws, Tile);
    } else {
        const int m0 = (bid - GRID_J) * 64;
        gemm_body<INF,  false, true >(ev, WtV, evW1, nullptr, bias,    N_ROWS, 0, m0, As, Ws, Tile);
    }
}

// ---------------------------------------------------------------------------
// Fused score + softmax + weighted gather (all-bf16 gather set).
// ---------------------------------------------------------------------------
__global__ __launch_bounds__(256) void score_out(
    const unsigned short* __restrict__ tabJ, const unsigned short* __restrict__ tabW,
    const unsigned short* __restrict__ evW1, const unsigned short* __restrict__ ejh,
    const int* __restrict__ vj, const int* __restrict__ vw,
    const float* __restrict__ vvec, float* __restrict__ out)
{
    const int n = blockIdx.x;
    const int t = threadIdx.x;

    __shared__ float  s_ev[128];
    __shared__ float  s_v[128];
    __shared__ int    s_j[32];
    __shared__ int    s_w[32];
    __shared__ float  s_a[32];
    __shared__ float2 s_red[2][128];

    if (t < 128) {
        s_ev[t] = bfu(evW1[(size_t)n * 128 + t]);
        s_v[t]  = vvec[t];
    } else if (t < 160) {
        int k = t - 128;
        s_j[k] = vj[n * KNBR + k];
        s_w[k] = vw[n * KNBR + k];
    }
    __syncthreads();

    // ---- scores: thread t -> neighbor k = t>>3, 16 channels ----
    const int k  = t >> 3;
    const int cg = t & 7;
    const int j  = s_j[k];
    const int w  = s_w[k];

    float x = 0.f;
    {
        const uint4* tj4 = (const uint4*)(tabJ + (size_t)j * 128 + cg * 16);
        const uint4* tw4 = (const uint4*)(tabW + (size_t)w * 128 + cg * 16);
        uint4 ja0 = tj4[0], ja1 = tj4[1];          // issue all 4 loads first
        uint4 wa0 = tw4[0], wa1 = tw4[1];
        unsigned jw[8] = {ja0.x, ja0.y, ja0.z, ja0.w, ja1.x, ja1.y, ja1.z, ja1.w};
        unsigned ww[8] = {wa0.x, wa0.y, wa0.z, wa0.w, wa1.x, wa1.y, wa1.z, wa1.w};
        #pragma unroll
        for (int p = 0; p < 8; p++) {
            int c0 = cg * 16 + p * 2;
            float av0 = s_ev[c0]     + bfu((unsigned short)(jw[p] & 0xffff))
                                     + bfu((unsigned short)(ww[p] & 0xffff));
            float av1 = s_ev[c0 + 1] + bfu((unsigned short)(jw[p] >> 16))
                                     + bfu((unsigned short)(ww[p] >> 16));
            x = fmaf(fmaxf(av0, 0.f), s_v[c0], x);
            x = fmaf(fmaxf(av1, 0.f), s_v[c0 + 1], x);
        }
    }
    x += __shfl_xor(x, 1);
    x += __shfl_xor(x, 2);
    x += __shfl_xor(x, 4);
    if (cg == 0) s_a[k] = x;
    __syncthreads();

    // ---- softmax over K=32 ----
    if (t < 32) {
        float xi = s_a[t];
        float mx = xi;
        #pragma unroll
        for (int m = 16; m >= 1; m >>= 1) mx = fmaxf(mx, __shfl_xor(mx, m));
        float e = __expf(xi - mx);
        float s = e;
        #pragma unroll
        for (int m = 16; m >= 1; m >>= 1) s += __shfl_xor(s, m);
        s_a[t] = e / s;
    }
    __syncthreads();

    // ---- weighted gather: thread owns feature pair p, k-half h ----
    const int p = t & 127;
    const int h = t >> 7;
    unsigned uu[16];
    float    aa[16];
    #pragma unroll
    for (int kk = 0; kk < 16; kk++) {          // issue all 16 loads first
        int k2 = h * 16 + kk;
        int j2 = s_j[k2];
        aa[kk] = s_a[k2];
        uu[kk] = j2 ? *(const unsigned*)(ejh + (size_t)(j2 - 1) * 256 + p * 2) : 0u;
    }
    float2 accv = {0.f, 0.f};
    #pragma unroll
    for (int kk = 0; kk < 16; kk++) {
        accv.x = fmaf(aa[kk], bfu((unsigned short)(uu[kk] & 0xffff)), accv.x);
        accv.y = fmaf(aa[kk], bfu((unsigned short)(uu[kk] >> 16)),    accv.y);
    }
    s_red[h][p] = accv;
    __syncthreads();
    if (t < 128) {
        float2 a0 = s_red[0][t], a1 = s_red[1][t];
        f32x2 r = {a0.x + a1.x, a0.y + a1.y};
        __builtin_nontemporal_store(r, (f32x2*)(out + (size_t)n * 256 + t * 2));
    }
}

// ---------------------------------------------------------------------------
extern "C" void kernel_launch(void* const* d_in, const int* in_sizes, int n_in,
                              void* d_out, int out_size, void* d_ws, size_t ws_size,
                              hipStream_t stream)
{
    const float* ev = (const float*)d_in[0];
    const float* ej = (const float*)d_in[1];
    const float* ew = (const float*)d_in[2];
    const int*   vj = (const int*)d_in[3];
    const int*   vw = (const int*)d_in[4];
    const float* W1 = (const float*)d_in[5];   // [320][128]
    const float* W2 = (const float*)d_in[6];   // [256][128]
    const float* b  = (const float*)d_in[7];   // [128]
    const float* v  = (const float*)d_in[8];   // [128]
    float* out = (float*)d_out;

    const float* W1v = W1;                     // rows 0..255
    const float* W1w = W1 + 256 * 128;         // rows 256..319

    // workspace layout (bf16), ~107.8 MB
    unsigned short* tabJ = (unsigned short*)d_ws;                      // (M+1)*128
    unsigned short* tabW = tabJ + (size_t)(M_ROWS + 1) * 128;          // (M+1)*128
    unsigned short* ejh  = tabW + (size_t)(M_ROWS + 1) * 128;          // M*256
    unsigned short* evW1 = ejh  + (size_t)M_ROWS * 256;                // N*128
    unsigned short* WtJ  = evW1 + (size_t)N_ROWS * 128;                // 128*256
    unsigned short* WtW  = WtJ  + 128 * 256;                           // 128*64
    unsigned short* WtV  = WtW  + 128 * 64;                            // 128*256

    prep_wt<<<288, 256, 0, stream>>>(W2, W1w, W1v, WtJ, WtW, WtV, tabJ, tabW);
    tables_fused<<<GRID_J + GRID_V, 256, 0, stream>>>(ej, ew, ev, WtJ, WtW, WtV,
                                                      tabJ, tabW, evW1, ejh, b);
    score_out<<<N_ROWS, 256, 0, stream>>>(tabJ, tabW, evW1, ejh, vj, vw, v, out);
}